// Round 3
// baseline (129.164 us; speedup 1.0000x reference)
//
#include <hip/hip_runtime.h>
#include <math.h>

#define FS 4096
#define FT 4096
#define TS 512           // candidates per LDS tile phase (float4 -> 8 KB per tile)
#define NPH 8            // phases (NPH * TS = 4096)
#define BIGF 3.0e38f
#define KEYINF 0xFFFFFFFFu

typedef float v2f __attribute__((ext_vector_type(2)));

__device__ __forceinline__ unsigned umin32(unsigned a, unsigned b) { return a < b ? a : b; }
__device__ __forceinline__ unsigned umax32(unsigned a, unsigned b) { return a < b ? b : a; }

// v_med3_u32: median of 3 — one VOP3 instruction on gfx950
__device__ __forceinline__ unsigned med3u(unsigned a, unsigned b, unsigned c) {
    unsigned d;
    asm("v_med3_u32 %0, %1, %2, %3" : "=v"(d) : "v"(a), "v"(b), "v"(c));
    return d;
}

// VOP3P packed fp32: 2 f32 ops per instruction (full-rate FP32 on CDNA4)
__device__ __forceinline__ v2f pk_fma(v2f a, v2f b, v2f c) {
    v2f d;
    asm("v_pk_fma_f32 %0, %1, %2, %3" : "=v"(d) : "v"(a), "v"(b), "v"(c));
    return d;
}
__device__ __forceinline__ v2f pk_add(v2f a, v2f b) {
    v2f d;
    asm("v_pk_add_f32 %0, %1, %2" : "=v"(d) : "v"(a), "v"(b));
    return d;
}

// async global->LDS, 16 B per lane; dest must be lane-linear (base + lane*16)
__device__ __forceinline__ void gl_lds16(const float4* g, float4* l) {
    __builtin_amdgcn_global_load_lds(
        (__attribute__((address_space(1))) void*)(g),
        (__attribute__((address_space(3))) void*)(l), 16, 0, 0);
}

// ---------- block reduction helper (all threads must call) ----------
__device__ __forceinline__ float block_reduce_sum(float v) {
    __shared__ float s[8];
    for (int o = 32; o > 0; o >>= 1) v += __shfl_down(v, o, 64);
    int lane = threadIdx.x & 63, wid = threadIdx.x >> 6;
    if (lane == 0) s[wid] = v;
    __syncthreads();
    int nw = blockDim.x >> 6;
    v = (threadIdx.x < (unsigned)nw) ? s[threadIdx.x] : 0.f;
    if (wid == 0)
        for (int o = 4; o > 0; o >>= 1) v += __shfl_down(v, o, 64);
    return v;  // valid in thread 0
}

// compare-exchange on packed keys
#define CE(x, y) { unsigned _n = umin32(x, y); y = umax32(x, y); x = _n; }

// bitonic merge across 32-lane seg groups of sorted-6 lists (INF-pad to 8);
// all lanes end with the merged top-6.
__device__ __forceinline__ void merge32(unsigned s[6]) {
    #pragma unroll
    for (int m = 1; m <= 16; m <<= 1) {
        unsigned b0 = __shfl_xor(s[0], m, 64), b1 = __shfl_xor(s[1], m, 64);
        unsigned b2 = __shfl_xor(s[2], m, 64), b3 = __shfl_xor(s[3], m, 64);
        unsigned b4 = __shfl_xor(s[4], m, 64), b5 = __shfl_xor(s[5], m, 64);
        unsigned l0 = s[0], l1 = s[1];
        unsigned l2 = umin32(s[2], b5), l3 = umin32(s[3], b4);
        unsigned l4 = umin32(s[4], b3), l5 = umin32(s[5], b2);
        unsigned l6 = b1, l7 = b0;
        CE(l0, l4) CE(l1, l5) CE(l2, l6) CE(l3, l7)
        CE(l0, l2) CE(l1, l3) CE(l4, l6) CE(l5, l7)
        CE(l0, l1) CE(l2, l3) CE(l4, l5) CE(l6, l7)
        s[0] = l0; s[1] = l1; s[2] = l2; s[3] = l3; s[4] = l4; s[5] = l5;
    }
}

// ---------- precompute barycenters; zero the output accumulator ----------
// Candidate arrays sbc2/tbc2 use a PAIRED PLANE layout for packed-fp32 reads:
// per 1024-candidate tile, pair p of group g couples candidates (a, b=a+32),
// a = tile*1024 + g*64 + p  (g in [0,16), p in [0,32)).
//   plane0 float4[tile*1024 + g*32 + p]      = (xa, xb, ya, yb)
//   plane1 float4[tile*1024 + 512 + g*32+p]  = (za, zb, wa, wb)
// where (x,y,z,w) is the candidate form (-2x,-2y,-2z,|c|^2):
//   dist = p2 + dot3(p, c.xyz) + c.w
// sbcr: raw source barycenter with .w = |bc|^2 (forward query points)
__global__ __launch_bounds__(64) void k_prep(
        const float* __restrict__ sv, const int* __restrict__ sf,
        const float* __restrict__ tv, const int* __restrict__ tf,
        float4* __restrict__ sbc2, float4* __restrict__ tbc2,
        float4* __restrict__ sbcr, float* __restrict__ out) {
    int i = blockIdx.x * 64 + threadIdx.x;
    if (i == 0) out[0] = 0.f;
    if (i >= FS) return;
    const float third = 1.f / 3.f;
    int a = sf[3*i], b = sf[3*i+1], c = sf[3*i+2];
    float x = (sv[3*a  ] + sv[3*b  ] + sv[3*c  ]) * third;
    float y = (sv[3*a+1] + sv[3*b+1] + sv[3*c+1]) * third;
    float z = (sv[3*a+2] + sv[3*b+2] + sv[3*c+2]) * third;
    float n2 = x*x + y*y + z*z;
    sbcr[i] = make_float4(x, y, z, n2);
    int ta = tf[i], tb = tf[FT + i], tc = tf[2*FT + i];
    float tx = (tv[3*ta  ] + tv[3*tb  ] + tv[3*tc  ]) * third;
    float ty = (tv[3*ta+1] + tv[3*tb+1] + tv[3*tc+1]) * third;
    float tz = (tv[3*ta+2] + tv[3*tb+2] + tv[3*tc+2]) * third;
    float tn2 = tx*tx + ty*ty + tz*tz;

    // paired-plane scatter
    int tt = i >> 10, cc = i & 1023;
    int g = cc >> 6, half = (cc >> 5) & 1, pp = cc & 31;
    int lo4 = tt*1024 + g*32 + pp, hi4 = lo4 + 512;
    float* S = (float*)sbc2;
    S[4*lo4 + half]     = -2.f*x;  S[4*lo4 + 2 + half] = -2.f*y;
    S[4*hi4 + half]     = -2.f*z;  S[4*hi4 + 2 + half] = n2;
    float* T = (float*)tbc2;
    T[4*lo4 + half]     = -2.f*tx; T[4*lo4 + 2 + half] = -2.f*ty;
    T[4*hi4 + half]     = -2.f*tz; T[4*hi4 + 2 + half] = tn2;
}

// ---------- fused main kernel: 1152 blocks x 256 threads ----------
// TS=512, 8 phases, global_load_lds staging. LDS = 2 x 8 KB tiles (~16.5 KB)
// -> 8 blocks/CU resident (wave-slot limited), whole 1152-block grid
// co-resident: no ramp/tail, TLP hides staging latency.
// Phase p stages paired-plane chunks: loBase = (p>>1)*1024 + (p&1)*256;
// tileX[0..256) <- plane0 chunk, tileX[256..512) <- plane1 chunk.
// Per-lane candidate visit order identical to the TS=1024 version
// (jja = p*512 + seg, step 64, 8 jp/phase) -> bit-identical results.
// blocks [0,1024)    : reverse loss — 32 points/block
// blocks [1024,1152) : forward loss — 32 faces/block
__global__ __launch_bounds__(256, 8) void k_main(
        const float* __restrict__ sv, const int* __restrict__ sf,
        const float* __restrict__ fp,
        const float* __restrict__ r1u, const float* __restrict__ r2u,
        const float4* __restrict__ sbc2, const float4* __restrict__ tbc2,
        const float4* __restrict__ sbcr, float* __restrict__ out) {
    __shared__ float4 tileS[TS];
    __shared__ float4 tileT[TS];
    int tid  = threadIdx.x;
    int seg  = tid & 31;
    int slot = tid >> 5;
    float contrib = 0.f;

    if (blockIdx.x < 1024) {
        // ================= reverse =================
        int pt0  = blockIdx.x * 32 + slot * 4;   // this thread's 4 points
        int face = pt0 >> 3;                      // all 4 share one face

        int a = sf[3*face], b = sf[3*face+1], c = sf[3*face+2];
        float ax = sv[3*a], ay = sv[3*a+1], az = sv[3*a+2];
        float bx = sv[3*b], by = sv[3*b+1], bz = sv[3*b+2];
        float cx = sv[3*c], cy = sv[3*c+1], cz = sv[3*c+2];
        float4 r14 = ((const float4*)r1u)[pt0 >> 2];
        float4 r24 = ((const float4*)r2u)[pt0 >> 2];
        v2f pxb[4], pyb[4], pzb[4], p2b[4];
        {
            float r1a[4] = {r14.x, r14.y, r14.z, r14.w};
            float r2a[4] = {r24.x, r24.y, r24.z, r24.w};
            #pragma unroll
            for (int i = 0; i < 4; ++i) {
                float r1 = sqrtf(r1a[i]);
                float w1 = 1.f - r1, w2 = r1 * (1.f - r2a[i]), w3 = r1 * r2a[i];
                float px = w1*ax + w2*bx + w3*cx;
                float py = w1*ay + w2*by + w3*cy;
                float pz = w1*az + w2*bz + w3*cz;
                float p2 = px*px + py*py + pz*pz;
                pxb[i] = (v2f){px, px}; pyb[i] = (v2f){py, py};
                pzb[i] = (v2f){pz, pz}; p2b[i] = (v2f){p2, p2};
            }
        }

        // per-lane top-3 per point (min + 2 med3 per eval); exact merged top-6
        unsigned s0[4], s1[4], s2[4];
        #pragma unroll
        for (int i = 0; i < 4; ++i) { s0[i]=KEYINF; s1[i]=KEYINF; s2[i]=KEYINF; }
        v2f vm2[4];
        #pragma unroll
        for (int i = 0; i < 4; ++i) vm2[i] = (v2f){BIGF, BIGF};

        for (int p = 0; p < NPH; ++p) {
            int loB = ((p >> 1) << 10) + ((p & 1) << 8);   // float4 index base
            __syncthreads();                                // tile free
            gl_lds16(&sbc2[loB + tid],       &tileS[tid]);
            gl_lds16(&sbc2[loB + 512 + tid], &tileS[256 + tid]);
            gl_lds16(&tbc2[loB + tid],       &tileT[tid]);
            gl_lds16(&tbc2[loB + 512 + tid], &tileT[256 + tid]);
            __syncthreads();                                // vmcnt drained: ready
            // ---- src sort-scan: 8 pair-groups, 2 candidates (j, j+32) each ----
            unsigned jja = (unsigned)(p * TS + seg);
            #pragma unroll 4
            for (int jp = 0; jp < 8; ++jp) {
                float4 lo = tileS[(jp << 5) + seg];
                float4 hi = tileS[256 + (jp << 5) + seg];
                v2f cx2 = {lo.x, lo.y}, cy2 = {lo.z, lo.w};
                v2f cz2 = {hi.x, hi.y}, cw2 = {hi.z, hi.w};
                #pragma unroll
                for (int i = 0; i < 4; ++i) {
                    // d = |p-c|^2 (unclamped; tiny-negative rounding sorts last)
                    v2f d2 = pk_add(cw2, p2b[i]);
                    d2 = pk_fma(pzb[i], cz2, d2);
                    d2 = pk_fma(pyb[i], cy2, d2);
                    d2 = pk_fma(pxb[i], cx2, d2);
                    unsigned ka = (__float_as_uint(d2.x) & 0xFFFFF000u) | jja;
                    unsigned kb = (__float_as_uint(d2.y) & 0xFFFFF000u) | (jja + 32u);
                    unsigned n0 = umin32(s0[i], ka);
                    unsigned n1 = med3u(s0[i], s1[i], ka);
                    unsigned n2 = med3u(s1[i], s2[i], ka);
                    s0[i]=n0; s1[i]=n1; s2[i]=n2;
                    n0 = umin32(s0[i], kb);
                    n1 = med3u(s0[i], s1[i], kb);
                    n2 = med3u(s1[i], s2[i], kb);
                    s0[i]=n0; s1[i]=n1; s2[i]=n2;
                }
                jja += 64;
            }
            // ---- tgt min-scan ----
            #pragma unroll 4
            for (int jp = 0; jp < 8; ++jp) {
                float4 lo = tileT[(jp << 5) + seg];
                float4 hi = tileT[256 + (jp << 5) + seg];
                v2f cx2 = {lo.x, lo.y}, cy2 = {lo.z, lo.w};
                v2f cz2 = {hi.x, hi.y}, cw2 = {hi.z, hi.w};
                #pragma unroll
                for (int i = 0; i < 4; ++i) {
                    v2f t = pk_fma(pzb[i], cz2, cw2);
                    t = pk_fma(pyb[i], cy2, t);
                    t = pk_fma(pxb[i], cx2, t);
                    vm2[i].x = fminf(vm2[i].x, t.x);
                    vm2[i].y = fminf(vm2[i].y, t.y);
                }
            }
        }

        // ---- merges across the 32-lane seg group ----
        float vm[4];
        #pragma unroll
        for (int i = 0; i < 4; ++i) {
            float v = fminf(vm2[i].x, vm2[i].y);
            v = fminf(v, __shfl_xor(v, 1, 64));
            v = fminf(v, __shfl_xor(v, 2, 64));
            v = fminf(v, __shfl_xor(v, 4, 64));
            v = fminf(v, __shfl_xor(v, 8, 64));
            v = fminf(v, __shfl_xor(v, 16, 64));
            vm[i] = v;
        }

        float pf = fp[face];
        float csum = 0.f;
        #pragma unroll
        for (int i = 0; i < 4; ++i) {
            unsigned srt[6] = {s0[i], s1[i], s2[i], KEYINF, KEYINF, KEYINF};
            merge32(srt);
            if (seg == 0) {
                int   q0 = srt[0] & 0xFFF, q1 = srt[1] & 0xFFF, q2 = srt[2] & 0xFFF;
                int   q3 = srt[3] & 0xFFF, q4 = srt[4] & 0xFFF, q5 = srt[5] & 0xFFF;
                float d0 = __uint_as_float(srt[0] & 0xFFFFF000u);
                float d1 = __uint_as_float(srt[1] & 0xFFFFF000u);
                float d2 = __uint_as_float(srt[2] & 0xFFFFF000u);
                float d3 = __uint_as_float(srt[3] & 0xFFFFF000u);
                float d4 = __uint_as_float(srt[4] & 0xFFFFF000u);
                float d5 = __uint_as_float(srt[5] & 0xFFFFF000u);

                int skip = 5;
                if      (q0 == face) skip = 0;
                else if (q1 == face) skip = 1;
                else if (q2 == face) skip = 2;
                else if (q3 == face) skip = 3;
                else if (q4 == face) skip = 4;

                float s = 0.f;
                if (skip != 0) s += fp[q0] * d0;
                if (skip != 1) s += fp[q1] * d1;
                if (skip != 2) s += fp[q2] * d2;
                if (skip != 3) s += fp[q3] * d3;
                if (skip != 4) s += fp[q4] * d4;
                if (skip != 5) s += fp[q5] * d5;

                float mtd = fmaxf(vm[i] + p2b[i].x, 0.f);
                csum += pf * mtd + (1.f - pf) * (s * 0.2f);
            }
        }
        if (seg == 0) contrib = csum;
    } else {
        // ================= forward =================
        int f0 = (blockIdx.x - 1024) * 32 + slot * 4;   // this thread's 4 faces
        float qw[4];
        v2f qxb[4], qyb[4], qzb[4];
        #pragma unroll
        for (int i = 0; i < 4; ++i) {
            float4 q = sbcr[f0 + i];
            qxb[i] = (v2f){q.x, q.x}; qyb[i] = (v2f){q.y, q.y};
            qzb[i] = (v2f){q.z, q.z}; qw[i] = q.w;
        }
        v2f vf2[4];
        #pragma unroll
        for (int i = 0; i < 4; ++i) vf2[i] = (v2f){BIGF, BIGF};

        for (int p = 0; p < NPH; ++p) {
            int loB = ((p >> 1) << 10) + ((p & 1) << 8);
            __syncthreads();
            gl_lds16(&tbc2[loB + tid],       &tileT[tid]);
            gl_lds16(&tbc2[loB + 512 + tid], &tileT[256 + tid]);
            __syncthreads();
            #pragma unroll 4
            for (int jp = 0; jp < 8; ++jp) {
                float4 lo = tileT[(jp << 5) + seg];
                float4 hi = tileT[256 + (jp << 5) + seg];
                v2f cx2 = {lo.x, lo.y}, cy2 = {lo.z, lo.w};
                v2f cz2 = {hi.x, hi.y}, cw2 = {hi.z, hi.w};
                #pragma unroll
                for (int i = 0; i < 4; ++i) {
                    v2f t = pk_fma(qzb[i], cz2, cw2);
                    t = pk_fma(qyb[i], cy2, t);
                    t = pk_fma(qxb[i], cx2, t);
                    vf2[i].x = fminf(vf2[i].x, t.x);
                    vf2[i].y = fminf(vf2[i].y, t.y);
                }
            }
        }
        float vf[4];
        #pragma unroll
        for (int i = 0; i < 4; ++i) {
            float v = fminf(vf2[i].x, vf2[i].y);
            v = fminf(v, __shfl_xor(v, 1, 64));
            v = fminf(v, __shfl_xor(v, 2, 64));
            v = fminf(v, __shfl_xor(v, 4, 64));
            v = fminf(v, __shfl_xor(v, 8, 64));
            v = fminf(v, __shfl_xor(v, 16, 64));
            vf[i] = v;
        }
        if (seg == 0)
            contrib = fp[f0  ] * fmaxf(vf[0] + qw[0], 0.f)
                    + fp[f0+1] * fmaxf(vf[1] + qw[1], 0.f)
                    + fp[f0+2] * fmaxf(vf[2] + qw[2], 0.f)
                    + fp[f0+3] * fmaxf(vf[3] + qw[3], 0.f);
    }

    float tot = block_reduce_sum(contrib);
    if (tid == 0) atomicAdd(out, tot);
}

extern "C" void kernel_launch(void* const* d_in, const int* in_sizes, int n_in,
                              void* d_out, int out_size, void* d_ws, size_t ws_size,
                              hipStream_t stream) {
    const float* sv  = (const float*)d_in[0];   // (1,2048,3)
    const int*   sf  = (const int*)  d_in[1];   // (4096,3)
    const float* tv  = (const float*)d_in[2];   // (1,2048,3)
    const int*   tf  = (const int*)  d_in[3];   // (3,4096)
    const float* fp  = (const float*)d_in[4];   // (4096,)
    const float* r1u = (const float*)d_in[5];   // (4096,8)
    const float* r2u = (const float*)d_in[6];   // (4096,8)
    float* out = (float*)d_out;

    char* ws = (char*)d_ws;
    float4* sbc2 = (float4*)(ws);                 // 64 KB, paired-plane layout
    float4* tbc2 = (float4*)(ws + 65536);         // 64 KB, paired-plane layout
    float4* sbcr = (float4*)(ws + 131072);        // 64 KB

    k_prep<<<64,   64,  0, stream>>>(sv, sf, tv, tf, sbc2, tbc2, sbcr, out);
    k_main<<<1152, 256, 0, stream>>>(sv, sf, fp, r1u, r2u, sbc2, tbc2, sbcr, out);
}

// Round 4
// 112.616 us; speedup vs baseline: 1.1469x; 1.1469x over previous
//
#include <hip/hip_runtime.h>
#include <math.h>

#define FS 4096
#define FT 4096
#define TS 512           // candidates per LDS tile phase (float4 -> 8 KB per tile)
#define NPH 8            // phases (NPH * TS = 4096)
#define BIGF 3.0e38f
#define KEYINF 0xFFFFFFFFu

typedef float v2f __attribute__((ext_vector_type(2)));

__device__ __forceinline__ unsigned umin32(unsigned a, unsigned b) { return a < b ? a : b; }
__device__ __forceinline__ unsigned umax32(unsigned a, unsigned b) { return a < b ? b : a; }

// v_med3_u32: median of 3 — one VOP3 instruction on gfx950
__device__ __forceinline__ unsigned med3u(unsigned a, unsigned b, unsigned c) {
    unsigned d;
    asm("v_med3_u32 %0, %1, %2, %3" : "=v"(d) : "v"(a), "v"(b), "v"(c));
    return d;
}

// VOP3P packed fp32: 2 f32 ops per instruction (full-rate FP32 on CDNA4)
__device__ __forceinline__ v2f pk_fma(v2f a, v2f b, v2f c) {
    v2f d;
    asm("v_pk_fma_f32 %0, %1, %2, %3" : "=v"(d) : "v"(a), "v"(b), "v"(c));
    return d;
}
__device__ __forceinline__ v2f pk_add(v2f a, v2f b) {
    v2f d;
    asm("v_pk_add_f32 %0, %1, %2" : "=v"(d) : "v"(a), "v"(b));
    return d;
}

// async global->LDS, 16 B per lane; dest lane-linear (wave base + lane*16)
__device__ __forceinline__ void gl_lds16(const float4* g, float4* l) {
    __builtin_amdgcn_global_load_lds(
        (__attribute__((address_space(1))) void*)(g),
        (__attribute__((address_space(3))) void*)(l), 16, 0, 0);
}

// ---------- block reduction helper (all threads must call) ----------
__device__ __forceinline__ float block_reduce_sum(float v) {
    __shared__ float s[8];
    for (int o = 32; o > 0; o >>= 1) v += __shfl_down(v, o, 64);
    int lane = threadIdx.x & 63, wid = threadIdx.x >> 6;
    if (lane == 0) s[wid] = v;
    __syncthreads();
    int nw = blockDim.x >> 6;
    v = (threadIdx.x < (unsigned)nw) ? s[threadIdx.x] : 0.f;
    if (wid == 0)
        for (int o = 4; o > 0; o >>= 1) v += __shfl_down(v, o, 64);
    return v;  // valid in thread 0
}

// compare-exchange on packed keys
#define CE(x, y) { unsigned _n = umin32(x, y); y = umax32(x, y); x = _n; }

// bitonic merge across 32-lane seg groups of sorted-6 lists (INF-pad to 8);
// all lanes end with the merged top-6.
__device__ __forceinline__ void merge32(unsigned s[6]) {
    #pragma unroll
    for (int m = 1; m <= 16; m <<= 1) {
        unsigned b0 = __shfl_xor(s[0], m, 64), b1 = __shfl_xor(s[1], m, 64);
        unsigned b2 = __shfl_xor(s[2], m, 64), b3 = __shfl_xor(s[3], m, 64);
        unsigned b4 = __shfl_xor(s[4], m, 64), b5 = __shfl_xor(s[5], m, 64);
        unsigned l0 = s[0], l1 = s[1];
        unsigned l2 = umin32(s[2], b5), l3 = umin32(s[3], b4);
        unsigned l4 = umin32(s[4], b3), l5 = umin32(s[5], b2);
        unsigned l6 = b1, l7 = b0;
        CE(l0, l4) CE(l1, l5) CE(l2, l6) CE(l3, l7)
        CE(l0, l2) CE(l1, l3) CE(l4, l6) CE(l5, l7)
        CE(l0, l1) CE(l2, l3) CE(l4, l5) CE(l6, l7)
        s[0] = l0; s[1] = l1; s[2] = l2; s[3] = l3; s[4] = l4; s[5] = l5;
    }
}

// ---------- precompute barycenters; zero the output accumulator ----------
// Candidate arrays sbc2/tbc2 use a PAIRED PLANE layout for packed-fp32 reads:
// per 1024-candidate tile, pair p of group g couples candidates (a, b=a+32),
// a = tile*1024 + g*64 + p  (g in [0,16), p in [0,32)).
//   plane0 float4[tile*1024 + g*32 + p]      = (xa, xb, ya, yb)
//   plane1 float4[tile*1024 + 512 + g*32+p]  = (za, zb, wa, wb)
// where (x,y,z,w) is the candidate form (-2x,-2y,-2z,|c|^2):
//   dist = p2 + dot3(p, c.xyz) + c.w
// sbcr: raw source barycenter with .w = |bc|^2 (forward query points)
__global__ __launch_bounds__(64) void k_prep(
        const float* __restrict__ sv, const int* __restrict__ sf,
        const float* __restrict__ tv, const int* __restrict__ tf,
        float4* __restrict__ sbc2, float4* __restrict__ tbc2,
        float4* __restrict__ sbcr, float* __restrict__ out) {
    int i = blockIdx.x * 64 + threadIdx.x;
    if (i == 0) out[0] = 0.f;
    if (i >= FS) return;
    const float third = 1.f / 3.f;
    int a = sf[3*i], b = sf[3*i+1], c = sf[3*i+2];
    float x = (sv[3*a  ] + sv[3*b  ] + sv[3*c  ]) * third;
    float y = (sv[3*a+1] + sv[3*b+1] + sv[3*c+1]) * third;
    float z = (sv[3*a+2] + sv[3*b+2] + sv[3*c+2]) * third;
    float n2 = x*x + y*y + z*z;
    sbcr[i] = make_float4(x, y, z, n2);
    int ta = tf[i], tb = tf[FT + i], tc = tf[2*FT + i];
    float tx = (tv[3*ta  ] + tv[3*tb  ] + tv[3*tc  ]) * third;
    float ty = (tv[3*ta+1] + tv[3*tb+1] + tv[3*tc+1]) * third;
    float tz = (tv[3*ta+2] + tv[3*tb+2] + tv[3*tc+2]) * third;
    float tn2 = tx*tx + ty*ty + tz*tz;

    // paired-plane scatter
    int tt = i >> 10, cc = i & 1023;
    int g = cc >> 6, half = (cc >> 5) & 1, pp = cc & 31;
    int lo4 = tt*1024 + g*32 + pp, hi4 = lo4 + 512;
    float* S = (float*)sbc2;
    S[4*lo4 + half]     = -2.f*x;  S[4*lo4 + 2 + half] = -2.f*y;
    S[4*hi4 + half]     = -2.f*z;  S[4*hi4 + 2 + half] = n2;
    float* T = (float*)tbc2;
    T[4*lo4 + half]     = -2.f*tx; T[4*lo4 + 2 + half] = -2.f*ty;
    T[4*hi4 + half]     = -2.f*tz; T[4*hi4 + 2 + half] = tn2;
}

// ---------- fused main kernel: 1152 blocks x 256 threads ----------
// TS=512, 8 phases, global_load_lds staging. LDS = 2 x 8 KB tiles (~16.9 KB).
// __launch_bounds__(256, 4): cap VGPR at 128 so the allocator lands at its
// NATURAL ~60 VGPR (r3's (256,8) forced 64-reg budget -> 32 VGPR + massive
// scratch spill: WRITE_SIZE 36 KB -> 82 MB, dur +33%. Occupancy comes from
// actual use: 60 VGPR -> 8 waves/SIMD; LDS 16.9 KB -> 9 blocks; wave slots
// -> 8 blocks/CU. Whole 1152-block grid co-resident, TLP hides staging.)
// Phase p stages paired-plane chunks: loBase = (p>>1)*1024 + (p&1)*256;
// tileX[0..256) <- plane0 chunk, tileX[256..512) <- plane1 chunk.
// Per-lane candidate visit order identical to the TS=1024 version
// (jja = p*512 + seg, step 64, 8 jp/phase) -> bit-identical results.
// blocks [0,1024)    : reverse loss — 32 points/block
// blocks [1024,1152) : forward loss — 32 faces/block
__global__ __launch_bounds__(256, 4) void k_main(
        const float* __restrict__ sv, const int* __restrict__ sf,
        const float* __restrict__ fp,
        const float* __restrict__ r1u, const float* __restrict__ r2u,
        const float4* __restrict__ sbc2, const float4* __restrict__ tbc2,
        const float4* __restrict__ sbcr, float* __restrict__ out) {
    __shared__ float4 tileS[TS];
    __shared__ float4 tileT[TS];
    int tid  = threadIdx.x;
    int seg  = tid & 31;
    int slot = tid >> 5;
    float contrib = 0.f;

    if (blockIdx.x < 1024) {
        // ================= reverse =================
        int pt0  = blockIdx.x * 32 + slot * 4;   // this thread's 4 points
        int face = pt0 >> 3;                      // all 4 share one face

        int a = sf[3*face], b = sf[3*face+1], c = sf[3*face+2];
        float ax = sv[3*a], ay = sv[3*a+1], az = sv[3*a+2];
        float bx = sv[3*b], by = sv[3*b+1], bz = sv[3*b+2];
        float cx = sv[3*c], cy = sv[3*c+1], cz = sv[3*c+2];
        float4 r14 = ((const float4*)r1u)[pt0 >> 2];
        float4 r24 = ((const float4*)r2u)[pt0 >> 2];
        v2f pxb[4], pyb[4], pzb[4], p2b[4];
        {
            float r1a[4] = {r14.x, r14.y, r14.z, r14.w};
            float r2a[4] = {r24.x, r24.y, r24.z, r24.w};
            #pragma unroll
            for (int i = 0; i < 4; ++i) {
                float r1 = sqrtf(r1a[i]);
                float w1 = 1.f - r1, w2 = r1 * (1.f - r2a[i]), w3 = r1 * r2a[i];
                float px = w1*ax + w2*bx + w3*cx;
                float py = w1*ay + w2*by + w3*cy;
                float pz = w1*az + w2*bz + w3*cz;
                float p2 = px*px + py*py + pz*pz;
                pxb[i] = (v2f){px, px}; pyb[i] = (v2f){py, py};
                pzb[i] = (v2f){pz, pz}; p2b[i] = (v2f){p2, p2};
            }
        }

        // per-lane top-3 per point (min + 2 med3 per eval); exact merged top-6
        unsigned s0[4], s1[4], s2[4];
        #pragma unroll
        for (int i = 0; i < 4; ++i) { s0[i]=KEYINF; s1[i]=KEYINF; s2[i]=KEYINF; }
        v2f vm2[4];
        #pragma unroll
        for (int i = 0; i < 4; ++i) vm2[i] = (v2f){BIGF, BIGF};

        for (int p = 0; p < NPH; ++p) {
            int loB = ((p >> 1) << 10) + ((p & 1) << 8);   // float4 index base
            __syncthreads();                                // tile free
            gl_lds16(&sbc2[loB + tid],       &tileS[tid]);
            gl_lds16(&sbc2[loB + 512 + tid], &tileS[256 + tid]);
            gl_lds16(&tbc2[loB + tid],       &tileT[tid]);
            gl_lds16(&tbc2[loB + 512 + tid], &tileT[256 + tid]);
            __syncthreads();                                // vmcnt drained: ready
            // ---- src sort-scan: 8 pair-groups, 2 candidates (j, j+32) each ----
            unsigned jja = (unsigned)(p * TS + seg);
            #pragma unroll 4
            for (int jp = 0; jp < 8; ++jp) {
                float4 lo = tileS[(jp << 5) + seg];
                float4 hi = tileS[256 + (jp << 5) + seg];
                v2f cx2 = {lo.x, lo.y}, cy2 = {lo.z, lo.w};
                v2f cz2 = {hi.x, hi.y}, cw2 = {hi.z, hi.w};
                #pragma unroll
                for (int i = 0; i < 4; ++i) {
                    // d = |p-c|^2 (unclamped; tiny-negative rounding sorts last)
                    v2f d2 = pk_add(cw2, p2b[i]);
                    d2 = pk_fma(pzb[i], cz2, d2);
                    d2 = pk_fma(pyb[i], cy2, d2);
                    d2 = pk_fma(pxb[i], cx2, d2);
                    unsigned ka = (__float_as_uint(d2.x) & 0xFFFFF000u) | jja;
                    unsigned kb = (__float_as_uint(d2.y) & 0xFFFFF000u) | (jja + 32u);
                    unsigned n0 = umin32(s0[i], ka);
                    unsigned n1 = med3u(s0[i], s1[i], ka);
                    unsigned n2 = med3u(s1[i], s2[i], ka);
                    s0[i]=n0; s1[i]=n1; s2[i]=n2;
                    n0 = umin32(s0[i], kb);
                    n1 = med3u(s0[i], s1[i], kb);
                    n2 = med3u(s1[i], s2[i], kb);
                    s0[i]=n0; s1[i]=n1; s2[i]=n2;
                }
                jja += 64;
            }
            // ---- tgt min-scan ----
            #pragma unroll 4
            for (int jp = 0; jp < 8; ++jp) {
                float4 lo = tileT[(jp << 5) + seg];
                float4 hi = tileT[256 + (jp << 5) + seg];
                v2f cx2 = {lo.x, lo.y}, cy2 = {lo.z, lo.w};
                v2f cz2 = {hi.x, hi.y}, cw2 = {hi.z, hi.w};
                #pragma unroll
                for (int i = 0; i < 4; ++i) {
                    v2f t = pk_fma(pzb[i], cz2, cw2);
                    t = pk_fma(pyb[i], cy2, t);
                    t = pk_fma(pxb[i], cx2, t);
                    vm2[i].x = fminf(vm2[i].x, t.x);
                    vm2[i].y = fminf(vm2[i].y, t.y);
                }
            }
        }

        // ---- merges across the 32-lane seg group ----
        float vm[4];
        #pragma unroll
        for (int i = 0; i < 4; ++i) {
            float v = fminf(vm2[i].x, vm2[i].y);
            v = fminf(v, __shfl_xor(v, 1, 64));
            v = fminf(v, __shfl_xor(v, 2, 64));
            v = fminf(v, __shfl_xor(v, 4, 64));
            v = fminf(v, __shfl_xor(v, 8, 64));
            v = fminf(v, __shfl_xor(v, 16, 64));
            vm[i] = v;
        }

        float pf = fp[face];
        float csum = 0.f;
        #pragma unroll
        for (int i = 0; i < 4; ++i) {
            unsigned srt[6] = {s0[i], s1[i], s2[i], KEYINF, KEYINF, KEYINF};
            merge32(srt);
            if (seg == 0) {
                int   q0 = srt[0] & 0xFFF, q1 = srt[1] & 0xFFF, q2 = srt[2] & 0xFFF;
                int   q3 = srt[3] & 0xFFF, q4 = srt[4] & 0xFFF, q5 = srt[5] & 0xFFF;
                float d0 = __uint_as_float(srt[0] & 0xFFFFF000u);
                float d1 = __uint_as_float(srt[1] & 0xFFFFF000u);
                float d2 = __uint_as_float(srt[2] & 0xFFFFF000u);
                float d3 = __uint_as_float(srt[3] & 0xFFFFF000u);
                float d4 = __uint_as_float(srt[4] & 0xFFFFF000u);
                float d5 = __uint_as_float(srt[5] & 0xFFFFF000u);

                int skip = 5;
                if      (q0 == face) skip = 0;
                else if (q1 == face) skip = 1;
                else if (q2 == face) skip = 2;
                else if (q3 == face) skip = 3;
                else if (q4 == face) skip = 4;

                float s = 0.f;
                if (skip != 0) s += fp[q0] * d0;
                if (skip != 1) s += fp[q1] * d1;
                if (skip != 2) s += fp[q2] * d2;
                if (skip != 3) s += fp[q3] * d3;
                if (skip != 4) s += fp[q4] * d4;
                if (skip != 5) s += fp[q5] * d5;

                float mtd = fmaxf(vm[i] + p2b[i].x, 0.f);
                csum += pf * mtd + (1.f - pf) * (s * 0.2f);
            }
        }
        if (seg == 0) contrib = csum;
    } else {
        // ================= forward =================
        int f0 = (blockIdx.x - 1024) * 32 + slot * 4;   // this thread's 4 faces
        float qw[4];
        v2f qxb[4], qyb[4], qzb[4];
        #pragma unroll
        for (int i = 0; i < 4; ++i) {
            float4 q = sbcr[f0 + i];
            qxb[i] = (v2f){q.x, q.x}; qyb[i] = (v2f){q.y, q.y};
            qzb[i] = (v2f){q.z, q.z}; qw[i] = q.w;
        }
        v2f vf2[4];
        #pragma unroll
        for (int i = 0; i < 4; ++i) vf2[i] = (v2f){BIGF, BIGF};

        for (int p = 0; p < NPH; ++p) {
            int loB = ((p >> 1) << 10) + ((p & 1) << 8);
            __syncthreads();
            gl_lds16(&tbc2[loB + tid],       &tileT[tid]);
            gl_lds16(&tbc2[loB + 512 + tid], &tileT[256 + tid]);
            __syncthreads();
            #pragma unroll 4
            for (int jp = 0; jp < 8; ++jp) {
                float4 lo = tileT[(jp << 5) + seg];
                float4 hi = tileT[256 + (jp << 5) + seg];
                v2f cx2 = {lo.x, lo.y}, cy2 = {lo.z, lo.w};
                v2f cz2 = {hi.x, hi.y}, cw2 = {hi.z, hi.w};
                #pragma unroll
                for (int i = 0; i < 4; ++i) {
                    v2f t = pk_fma(qzb[i], cz2, cw2);
                    t = pk_fma(qyb[i], cy2, t);
                    t = pk_fma(qxb[i], cx2, t);
                    vf2[i].x = fminf(vf2[i].x, t.x);
                    vf2[i].y = fminf(vf2[i].y, t.y);
                }
            }
        }
        float vf[4];
        #pragma unroll
        for (int i = 0; i < 4; ++i) {
            float v = fminf(vf2[i].x, vf2[i].y);
            v = fminf(v, __shfl_xor(v, 1, 64));
            v = fminf(v, __shfl_xor(v, 2, 64));
            v = fminf(v, __shfl_xor(v, 4, 64));
            v = fminf(v, __shfl_xor(v, 8, 64));
            v = fminf(v, __shfl_xor(v, 16, 64));
            vf[i] = v;
        }
        if (seg == 0)
            contrib = fp[f0  ] * fmaxf(vf[0] + qw[0], 0.f)
                    + fp[f0+1] * fmaxf(vf[1] + qw[1], 0.f)
                    + fp[f0+2] * fmaxf(vf[2] + qw[2], 0.f)
                    + fp[f0+3] * fmaxf(vf[3] + qw[3], 0.f);
    }

    float tot = block_reduce_sum(contrib);
    if (tid == 0) atomicAdd(out, tot);
}

extern "C" void kernel_launch(void* const* d_in, const int* in_sizes, int n_in,
                              void* d_out, int out_size, void* d_ws, size_t ws_size,
                              hipStream_t stream) {
    const float* sv  = (const float*)d_in[0];   // (1,2048,3)
    const int*   sf  = (const int*)  d_in[1];   // (4096,3)
    const float* tv  = (const float*)d_in[2];   // (1,2048,3)
    const int*   tf  = (const int*)  d_in[3];   // (3,4096)
    const float* fp  = (const float*)d_in[4];   // (4096,)
    const float* r1u = (const float*)d_in[5];   // (4096,8)
    const float* r2u = (const float*)d_in[6];   // (4096,8)
    float* out = (float*)d_out;

    char* ws = (char*)d_ws;
    float4* sbc2 = (float4*)(ws);                 // 64 KB, paired-plane layout
    float4* tbc2 = (float4*)(ws + 65536);         // 64 KB, paired-plane layout
    float4* sbcr = (float4*)(ws + 131072);        // 64 KB

    k_prep<<<64,   64,  0, stream>>>(sv, sf, tv, tf, sbc2, tbc2, sbcr, out);
    k_main<<<1152, 256, 0, stream>>>(sv, sf, fp, r1u, r2u, sbc2, tbc2, sbcr, out);
}